// Round 1
// baseline (842.846 us; speedup 1.0000x reference)
//
#include <hip/hip_runtime.h>
#include <math.h>

#define EPS    1e-6f
#define KTAPS  31
#define PAD    15
#define LROW   8192
#define NLAYER 10
#define T      32            // elements per thread
#define NT     256           // threads per block (one row per block)
#define WIN    (T + KTAPS - 1)  // 62
#define LDS_BODY (LROW + (LROW >> 5))  // 8448 floats, skewed layout
#define GUARD  16

// skew: +1 float every 32 -> chunk starts (stride 32 floats across lanes)
// land on distinct banks instead of all on bank 0.
#define SKEWED(j) ((j) + ((j) >> 5))   // arithmetic shift: j in [-15,-1] -> [-16,-2] (guard)

__global__ __launch_bounds__(NT, 2) void drl_kernel(
    const float* __restrict__ m,
    const float* __restrict__ psf,
    const float* __restrict__ alpha,
    float* __restrict__ out)
{
    __shared__ float raw[GUARD + LDS_BODY + GUARD];
    float* buf = raw + GUARD;   // buf[-16..-1] and buf[8448..8463] are zero guards

    const int row = blockIdx.x;
    const int t   = threadIdx.x;
    const float* mrow = m + (size_t)row * LROW;
    float*       orow = out + (size_t)row * LROW;

    // psf taps (wave-uniform, constant offsets -> scalar loads)
    float w[KTAPS];
#pragma unroll
    for (int k = 0; k < KTAPS; ++k) w[k] = psf[k];

    // zero conv guard bands (implements zero padding without bounds checks)
    if (t < GUARD) { raw[t] = 0.0f; raw[GUARD + LDS_BODY + t] = 0.0f; }

    // stage x into LDS with coalesced global reads
#pragma unroll
    for (int i = 0; i < T; ++i) {
        int j = t + NT * i;
        buf[SKEWED(j)] = mrow[j];
    }
    __syncthreads();

    float xreg[T], sreg[T];
    const int base = t * T;
#pragma unroll
    for (int i = 0; i < T; ++i) xreg[i] = buf[SKEWED(base + i)];
    __syncthreads();
    // s0 = 0.5 everywhere
#pragma unroll
    for (int i = 0; i < T; ++i) { sreg[i] = 0.5f; buf[SKEWED(base + i)] = 0.5f; }
    __syncthreads();

#pragma unroll 1   // keep code size ~1 layer body (I-cache)
    for (int layer = 0; layer < NLAYER; ++layer) {
        const float a = alpha[layer];
        float win[WIN];

        // ---- conv1: s_conv = conv(s, w) + EPS; ratio = x / s_conv ----
#pragma unroll
        for (int i = 0; i < WIN; ++i) win[i] = buf[SKEWED(base - PAD + i)];
        __syncthreads();                     // all reads of s done before overwrite
#pragma unroll
        for (int i = 0; i < T; ++i) {
            float acc = EPS;
#pragma unroll
            for (int k = 0; k < KTAPS; ++k) acc = fmaf(w[k], win[i + k], acc);
            buf[SKEWED(base + i)] = xreg[i] * __builtin_amdgcn_rcpf(acc);
        }
        __syncthreads();                     // ratio visible to all

        // ---- conv2: correction = conv(ratio, w_flip) + EPS ----
#pragma unroll
        for (int i = 0; i < WIN; ++i) win[i] = buf[SKEWED(base - PAD + i)];
        __syncthreads();                     // all reads of ratio done before overwrite
        const bool aone = (a == 1.0f);       // wave-uniform
#pragma unroll
        for (int i = 0; i < T; ++i) {
            float acc = EPS;
#pragma unroll
            for (int k = 0; k < KTAPS; ++k) acc = fmaf(w[KTAPS - 1 - k], win[i + k], acc);
            float corr = fmaxf(acc, EPS);
            corr = aone ? corr : powf(corr, a);
            float sv = fmaxf(sreg[i] * corr, EPS);
            sreg[i] = sv;
            buf[SKEWED(base + i)] = sv;
        }
        __syncthreads();                     // s visible for next layer
    }

    // coalesced store of final s
#pragma unroll
    for (int i = 0; i < T; ++i) {
        int j = t + NT * i;
        orow[j] = buf[SKEWED(j)];
    }
}

extern "C" void kernel_launch(void* const* d_in, const int* in_sizes, int n_in,
                              void* d_out, int out_size, void* d_ws, size_t ws_size,
                              hipStream_t stream) {
    const float* m     = (const float*)d_in[0];
    const float* psf   = (const float*)d_in[1];
    const float* alpha = (const float*)d_in[2];
    float* out = (float*)d_out;
    const int B = in_sizes[0] / LROW;   // 4096 rows
    drl_kernel<<<dim3(B), dim3(NT), 0, stream>>>(m, psf, alpha, out);
}

// Round 2
// 813.356 us; speedup vs baseline: 1.0363x; 1.0363x over previous
//
#include <hip/hip_runtime.h>
#include <math.h>

#define EPS    1e-6f
#define KTAPS  31
#define PAD    15
#define LROW   8192
#define NLAYER 10
#define T      32                 // elements per thread
#define NT     256                // threads per block (one row per block)
#define NCHUNK 256                // chunks of 32 per row
#define CST    36                 // chunk stride in floats (32 data + 4 pad) -> 16B aligned, conflict-free b128
#define FRONT  20                 // front guard floats (window reads reach float addr -20..-5)
#define BODY   (NCHUNK * CST)     // 9216
#define BACK   16                 // back guard (reads reach 9216..9231)
#define BUF_F  (FRONT + BODY + BACK)  // 9252 floats per buffer (multiple of 4 -> bufB stays 16B aligned)

// buffer layout: float addr(j) = (j>>5)*36 + (j&31); every 32-chunk contiguous & 16B aligned.
// window of thread t: floats [32t-16, 32t+48) = 16 aligned float4s:
//   seg A (4 q): f4 idx 9t-5+v      (chunk t-1, floats 16..31)
//   seg B (8 q): f4 idx 9t+v        (chunk t)
//   seg C (4 q): f4 idx 9(t+1)+v    (chunk t+1, floats 0..15)
// all addresses are 36t + const -> 8 consecutive lanes hit start-banks 4t mod 32 -> all 32 banks.

__global__ __launch_bounds__(NT, 2) void drl_kernel(
    const float* __restrict__ m,
    const float* __restrict__ psf,
    const float* __restrict__ alpha,
    float* __restrict__ out)
{
    __shared__ __align__(16) float raw[2 * BUF_F];
    float4* A4 = (float4*)(raw + FRONT);           // buffer A (s lives here at layer start)
    float4* B4 = (float4*)(raw + BUF_F + FRONT);   // buffer B (ratio)

    const int row = blockIdx.x;
    const int t   = threadIdx.x;
    const float* mrow = m + (size_t)row * LROW;
    float*       orow = out + (size_t)row * LROW;

    // psf taps -> wave-uniform scalar loads (SGPRs)
    float w[KTAPS];
#pragma unroll
    for (int k = 0; k < KTAPS; ++k) w[k] = psf[k];

    // zero guard bands of both buffers (never written afterwards)
    if (t < FRONT) { raw[t] = 0.0f; raw[BUF_F + t] = 0.0f; }
    if (t < BACK)  { raw[FRONT + BODY + t] = 0.0f; raw[BUF_F + FRONT + BODY + t] = 0.0f; }

    // stage x into B (coalesced float4 global loads), s0=0.5 into own chunk of A
    {
        const float4 half4 = make_float4(0.5f, 0.5f, 0.5f, 0.5f);
#pragma unroll
        for (int i = 0; i < 8; ++i) {
            float4 v = *(const float4*)(mrow + 4 * (t + NT * i));
            // j0 = 4(t+256i): chunk = (t>>3)+32i, quad-in-chunk = t&7
            B4[9 * ((t >> 3) + 32 * i) + (t & 7)] = v;
            A4[9 * t + i] = half4;
        }
    }
    __syncthreads();

    // x for this thread's chunk (from B; conv1 later overwrites only our own chunk -> safe)
    float xreg[T], sreg[T];
#pragma unroll
    for (int q = 0; q < 8; ++q) {
        float4 v = B4[9 * t + q];
        xreg[4*q] = v.x; xreg[4*q+1] = v.y; xreg[4*q+2] = v.z; xreg[4*q+3] = v.w;
    }
#pragma unroll
    for (int i = 0; i < T; ++i) sreg[i] = 0.5f;

#pragma unroll 1   // keep code size ~1 layer body
    for (int layer = 0; layer < NLAYER; ++layer) {
        const float a = alpha[layer];
        const bool aone = (a == 1.0f);       // wave-uniform
        float win[T + 2 * (PAD + 1)];        // 64: floats [base-16, base+48)

        // ---- conv1: read s-window from A, ratio = x/(conv(s,w)+EPS) -> B ----
#pragma unroll
        for (int v = 0; v < 4; ++v) {
            float4 q = A4[9 * t - 5 + v];
            win[4*v] = q.x; win[4*v+1] = q.y; win[4*v+2] = q.z; win[4*v+3] = q.w;
        }
#pragma unroll
        for (int v = 0; v < 8; ++v) {
            float4 q = A4[9 * t + v];
            win[16+4*v] = q.x; win[17+4*v] = q.y; win[18+4*v] = q.z; win[19+4*v] = q.w;
        }
#pragma unroll
        for (int v = 0; v < 4; ++v) {
            float4 q = A4[9 * (t + 1) + v];
            win[48+4*v] = q.x; win[49+4*v] = q.y; win[50+4*v] = q.z; win[51+4*v] = q.w;
        }
        {
            float o[T];
#pragma unroll
            for (int i = 0; i < T; ++i) {
                float acc = EPS;
#pragma unroll
                for (int k = 0; k < KTAPS; ++k) acc = fmaf(w[k], win[i + 1 + k], acc);
                o[i] = xreg[i] * __builtin_amdgcn_rcpf(acc);
            }
#pragma unroll
            for (int q = 0; q < 8; ++q)
                B4[9 * t + q] = make_float4(o[4*q], o[4*q+1], o[4*q+2], o[4*q+3]);
        }
        __syncthreads();   // ratio fully in B

        // ---- conv2: read ratio-window from B, s = max(s*corr^a, EPS) -> A ----
#pragma unroll
        for (int v = 0; v < 4; ++v) {
            float4 q = B4[9 * t - 5 + v];
            win[4*v] = q.x; win[4*v+1] = q.y; win[4*v+2] = q.z; win[4*v+3] = q.w;
        }
#pragma unroll
        for (int v = 0; v < 8; ++v) {
            float4 q = B4[9 * t + v];
            win[16+4*v] = q.x; win[17+4*v] = q.y; win[18+4*v] = q.z; win[19+4*v] = q.w;
        }
#pragma unroll
        for (int v = 0; v < 4; ++v) {
            float4 q = B4[9 * (t + 1) + v];
            win[48+4*v] = q.x; win[49+4*v] = q.y; win[50+4*v] = q.z; win[51+4*v] = q.w;
        }
        {
            float o[T];
#pragma unroll
            for (int i = 0; i < T; ++i) {
                float acc = EPS;
#pragma unroll
                for (int k = 0; k < KTAPS; ++k) acc = fmaf(w[KTAPS - 1 - k], win[i + 1 + k], acc);
                float corr = fmaxf(acc, EPS);
                corr = aone ? corr : powf(corr, a);
                float sv = fmaxf(sreg[i] * corr, EPS);
                sreg[i] = sv;
                o[i] = sv;
            }
#pragma unroll
            for (int q = 0; q < 8; ++q)
                A4[9 * t + q] = make_float4(o[4*q], o[4*q+1], o[4*q+2], o[4*q+3]);
        }
        __syncthreads();   // s fully in A for next layer
    }

    // coalesced float4 store of final s from A
#pragma unroll
    for (int i = 0; i < 8; ++i) {
        float4 v = A4[9 * ((t >> 3) + 32 * i) + (t & 7)];
        *(float4*)(orow + 4 * (t + NT * i)) = v;
    }
}

extern "C" void kernel_launch(void* const* d_in, const int* in_sizes, int n_in,
                              void* d_out, int out_size, void* d_ws, size_t ws_size,
                              hipStream_t stream) {
    const float* m     = (const float*)d_in[0];
    const float* psf   = (const float*)d_in[1];
    const float* alpha = (const float*)d_in[2];
    float* out = (float*)d_out;
    const int B = in_sizes[0] / LROW;   // 4096 rows
    drl_kernel<<<dim3(B), dim3(NT), 0, stream>>>(m, psf, alpha, out);
}

// Round 3
// 770.061 us; speedup vs baseline: 1.0945x; 1.0562x over previous
//
#include <hip/hip_runtime.h>
#include <math.h>

#define EPS    1e-6f
#define KTAPS  31
#define PAD    15
#define LROW   8192
#define NLAYER 10
#define T      16                 // elements per thread (half-chunk)
#define NT     512                // threads per block, one row per block
#define NCHUNK 256                // 32-float chunks per row
#define CST    36                 // chunk stride in floats (32 data + 4 pad)
#define FRONT  20                 // guard floats in front (reads reach addr -20..-5)
#define BODY   (NCHUNK * CST)     // 9216
#define BACK   16                 // guard floats behind (reads reach 9216..9231)
#define BUF_F  (FRONT + BODY + BACK)  // 9252 floats per buffer

// float index j -> LDS float addr (j>>5)*36 + (j&31).
// half-chunk u covers j=[16u,16u+16): 4 contiguous, 16B-aligned float4s.
__device__ __forceinline__ int f4addr(int u) {
    return 9 * (u >> 1) + 4 * (u & 1);    // float4 index; u=-1 -> -5 (front guard)
}

__device__ __forceinline__ float sgpr_f(float v) {
    return __int_as_float(__builtin_amdgcn_readfirstlane(__float_as_int(v)));
}

__global__ __launch_bounds__(NT, 4) void drl_kernel(
    const float* __restrict__ m,
    const float* __restrict__ psf,
    const float* __restrict__ alpha,
    float* __restrict__ out)
{
    __shared__ __align__(16) float raw[2 * BUF_F];
    float4* A4 = (float4*)(raw + FRONT);           // s lives here at layer start
    float4* B4 = (float4*)(raw + BUF_F + FRONT);   // ratio / x staging

    const int row = blockIdx.x;
    const int t   = threadIdx.x;
    const float* mrow = m + (size_t)row * LROW;
    float*       orow = out + (size_t)row * LROW;

    // psf taps forced into SGPRs: v_fma_f32 can take one SGPR operand for free
    float w[KTAPS];
#pragma unroll
    for (int k = 0; k < KTAPS; ++k) w[k] = sgpr_f(psf[k]);

    // zero guard bands of both buffers (never written afterwards)
    if (t < FRONT) { raw[t] = 0.0f; raw[BUF_F + t] = 0.0f; }
    if (t < BACK)  { raw[FRONT + BODY + t] = 0.0f; raw[BUF_F + FRONT + BODY + t] = 0.0f; }

    // stage x into B (coalesced float4 global loads); s0=0.5 into own half-chunk of A
    {
        const float4 half4 = make_float4(0.5f, 0.5f, 0.5f, 0.5f);
#pragma unroll
        for (int i = 0; i < 4; ++i) {
            float4 v = *(const float4*)(mrow + 4 * (t + NT * i));
            // j0 = 4(t+512i): f4 index = 9*((t>>3)+64i) + (t&7)
            B4[9 * ((t >> 3) + 64 * i) + (t & 7)] = v;
        }
        const int a0 = f4addr(t);
#pragma unroll
        for (int q = 0; q < 4; ++q) A4[a0 + q] = half4;
    }
    __syncthreads();

    // x for this thread's half-chunk (conv1 only ever overwrites our own region of B)
    float xreg[T], sreg[T];
    {
        const int a0 = f4addr(t);
#pragma unroll
        for (int q = 0; q < 4; ++q) {
            float4 v = B4[a0 + q];
            xreg[4*q] = v.x; xreg[4*q+1] = v.y; xreg[4*q+2] = v.z; xreg[4*q+3] = v.w;
        }
    }
#pragma unroll
    for (int i = 0; i < T; ++i) sreg[i] = 0.5f;

#pragma unroll 1
    for (int layer = 0; layer < NLAYER; ++layer) {
        const float a = sgpr_f(alpha[layer]);   // SGPR -> scalar branch below
        float win[T + 2 * (PAD + 1)];           // 48 floats: j in [16t-16, 16t+32)

        // ---- conv1: window of s from A; ratio = x/(conv(s,w)+EPS) -> B ----
#pragma unroll
        for (int g = 0; g < 3; ++g) {
            const int ag = f4addr(t - 1 + g);
#pragma unroll
            for (int v = 0; v < 4; ++v) {
                float4 q = A4[ag + v];
                win[16*g+4*v] = q.x; win[16*g+4*v+1] = q.y;
                win[16*g+4*v+2] = q.z; win[16*g+4*v+3] = q.w;
            }
        }
        {
            float o[T];
#pragma unroll
            for (int i = 0; i < T; ++i) {
                float acc = EPS;
#pragma unroll
                for (int k = 0; k < KTAPS; ++k) acc = fmaf(w[k], win[i + 1 + k], acc);
                o[i] = xreg[i] * __builtin_amdgcn_rcpf(acc);
            }
            const int a0 = f4addr(t);
#pragma unroll
            for (int q = 0; q < 4; ++q)
                B4[a0 + q] = make_float4(o[4*q], o[4*q+1], o[4*q+2], o[4*q+3]);
        }
        __syncthreads();   // ratio fully in B

        // ---- conv2: window of ratio from B; s = max(s*corr^a, EPS) -> A ----
#pragma unroll
        for (int g = 0; g < 3; ++g) {
            const int ag = f4addr(t - 1 + g) + (BUF_F / 4) * 0;  // B below
#pragma unroll
            for (int v = 0; v < 4; ++v) {
                float4 q = B4[f4addr(t - 1 + g) + v];
                win[16*g+4*v] = q.x; win[16*g+4*v+1] = q.y;
                win[16*g+4*v+2] = q.z; win[16*g+4*v+3] = q.w;
            }
            (void)ag;
        }
        {
            float corr[T];
#pragma unroll
            for (int i = 0; i < T; ++i) {
                float acc = EPS;
#pragma unroll
                for (int k = 0; k < KTAPS; ++k) acc = fmaf(w[KTAPS - 1 - k], win[i + 1 + k], acc);
                corr[i] = fmaxf(acc, EPS);
            }
            if (a != 1.0f) {   // scalar (SGPR) compare -> s_cbranch skips powf entirely
#pragma unroll
                for (int i = 0; i < T; ++i) corr[i] = powf(corr[i], a);
            }
            const int a0 = f4addr(t);
#pragma unroll
            for (int q = 0; q < 4; ++q) {
                float s0 = fmaxf(sreg[4*q]   * corr[4*q],   EPS);
                float s1 = fmaxf(sreg[4*q+1] * corr[4*q+1], EPS);
                float s2 = fmaxf(sreg[4*q+2] * corr[4*q+2], EPS);
                float s3 = fmaxf(sreg[4*q+3] * corr[4*q+3], EPS);
                sreg[4*q] = s0; sreg[4*q+1] = s1; sreg[4*q+2] = s2; sreg[4*q+3] = s3;
                A4[a0 + q] = make_float4(s0, s1, s2, s3);
            }
        }
        __syncthreads();   // s fully in A for next layer
    }

    // coalesced float4 store of final s from A
#pragma unroll
    for (int i = 0; i < 4; ++i) {
        float4 v = A4[9 * ((t >> 3) + 64 * i) + (t & 7)];
        *(float4*)(orow + 4 * (t + NT * i)) = v;
    }
}

extern "C" void kernel_launch(void* const* d_in, const int* in_sizes, int n_in,
                              void* d_out, int out_size, void* d_ws, size_t ws_size,
                              hipStream_t stream) {
    const float* m     = (const float*)d_in[0];
    const float* psf   = (const float*)d_in[1];
    const float* alpha = (const float*)d_in[2];
    float* out = (float*)d_out;
    const int B = in_sizes[0] / LROW;   // 4096 rows
    drl_kernel<<<dim3(B), dim3(NT), 0, stream>>>(m, psf, alpha, out);
}